// Round 1
// baseline (21431.601 us; speedup 1.0000x reference)
//
#include <hip/hip_runtime.h>

// ---------------------------------------------------------------------------
// GRU: hs = scan(h, x)  with
//   xzr = x @ W_zr^T + b_zr ; xh = x @ W_h^T + b_h          (parallel GEMM)
//   z = sig(xz + h U_z^T); r = sig(xr + h U_r^T)
//   h~ = tanh(xh + (r*h) U_h^T); h = (1-z)h + z h~          (sequential scan)
//
// Phase 1: convert inputs to bf16, GEMM P = Xbf @ Wbf^T + bias (bf16 out).
// Phase 2: persistent scan kernel: 64 wgs = 2 independent batch-groups x 32
//          wgs; weights in VGPRs; flag-barrier between matmul phases.
// ---------------------------------------------------------------------------

typedef __attribute__((ext_vector_type(8))) __bf16 bf16x8;
typedef __attribute__((ext_vector_type(4))) float f32x4;
typedef unsigned short ushort_t;

#define DIM_ 1024
#define BATCH_ 32
#define T_ 1024
#define NC_ 3072  // 3*DIM

// workspace layout (bytes)
static constexpr size_t OFF_P     = 0;                    // bf16 32768x3072
static constexpr size_t OFF_XBF   = 201326592;            // bf16 32768x1024
static constexpr size_t OFF_WBF   = OFF_XBF + 67108864;   // bf16 3072x1024
static constexpr size_t OFF_UZR   = OFF_WBF + 6291456;    // bf16 2048x1024
static constexpr size_t OFF_UH    = OFF_UZR + 4194304;    // bf16 1024x1024
static constexpr size_t OFF_HB    = OFF_UH  + 2097152;    // bf16 32x1024
static constexpr size_t OFF_RH    = OFF_HB  + 65536;      // bf16 32x1024
static constexpr size_t OFF_FLAGS = OFF_RH  + 65536;      // 256 B
// total ~268.1 MiB of d_ws

__device__ __forceinline__ float b2f(ushort_t u) {
  union { float f; unsigned i; } v;
  v.i = ((unsigned)u) << 16;
  return v.f;
}
__device__ __forceinline__ ushort_t f2b(float f) {  // round-to-nearest-even
  union { float f; unsigned i; } v;
  v.f = f;
  unsigned r = v.i + 0x7fffu + ((v.i >> 16) & 1u);
  return (ushort_t)(r >> 16);
}

// ------------------------------- converts ----------------------------------
__global__ void cvt_f32_bf16x4(const float4* __restrict__ src,
                               uint2* __restrict__ dst, int n4) {
  int i = blockIdx.x * blockDim.x + threadIdx.x;
  int st = gridDim.x * blockDim.x;
  for (; i < n4; i += st) {
    float4 v = src[i];
    unsigned a = (unsigned)f2b(v.x) | ((unsigned)f2b(v.y) << 16);
    unsigned b = (unsigned)f2b(v.z) | ((unsigned)f2b(v.w) << 16);
    dst[i] = make_uint2(a, b);
  }
}

__global__ void zero_flags(unsigned* f) { f[threadIdx.x] = 0u; }

// ------------------------------- GEMM --------------------------------------
// C[i,n] = sum_k A[i,k]*Bm[n,k] + bias(n);  A 32768x1024, Bm 3072x1024 (bf16)
__global__ __launch_bounds__(256) void gemm_xw(
    const ushort_t* __restrict__ A, const ushort_t* __restrict__ Bm,
    const float* __restrict__ bzr, const float* __restrict__ bh,
    ushort_t* __restrict__ C) {
  __shared__ ushort_t As[128][40];  // +8 pad: break 64B-stride bank conflicts
  __shared__ ushort_t Bs[128][40];
  const int bi = blockIdx.x;
  const int p = bi / 192;              // 32 panels of 8 i-tiles x 24 n-tiles
  const int q = bi % 192;
  const int i0 = (p * 8 + (q & 7)) * 128;
  const int n0 = (q >> 3) * 128;
  const int tid = threadIdx.x;
  const int w = tid >> 6, l = tid & 63;
  const int wr = w >> 1, wc = w & 1;
  const int quad = l >> 4, lr = l & 15;

  f32x4 acc[4][4] = {};
  for (int kc = 0; kc < 1024; kc += 32) {
    __syncthreads();
#pragma unroll
    for (int j = 0; j < 2; ++j) {
      int c = j * 256 + tid;  // 0..511 16B chunks
      int r = c >> 2, pp = c & 3;
      *(int4*)(&As[r][pp * 8]) =
          *(const int4*)(A + (size_t)(i0 + r) * 1024 + kc + pp * 8);
      *(int4*)(&Bs[r][pp * 8]) =
          *(const int4*)(Bm + (size_t)(n0 + r) * 1024 + kc + pp * 8);
    }
    __syncthreads();
    bf16x8 af[4], bfr[4];
#pragma unroll
    for (int mb = 0; mb < 4; ++mb)
      af[mb] = *(const bf16x8*)(&As[wr * 64 + mb * 16 + lr][quad * 8]);
#pragma unroll
    for (int nb = 0; nb < 4; ++nb)
      bfr[nb] = *(const bf16x8*)(&Bs[wc * 64 + nb * 16 + lr][quad * 8]);
#pragma unroll
    for (int mb = 0; mb < 4; ++mb)
#pragma unroll
      for (int nb = 0; nb < 4; ++nb)
        acc[mb][nb] = __builtin_amdgcn_mfma_f32_16x16x32_bf16(
            af[mb], bfr[nb], acc[mb][nb], 0, 0, 0);
  }
#pragma unroll
  for (int nb = 0; nb < 4; ++nb) {
    int col = n0 + wc * 64 + nb * 16 + lr;
    float bias = (col < 2048) ? bzr[col] : bh[col - 2048];
#pragma unroll
    for (int mb = 0; mb < 4; ++mb) {
#pragma unroll
      for (int reg = 0; reg < 4; ++reg) {
        int row = i0 + wr * 64 + mb * 16 + quad * 4 + reg;
        C[(size_t)row * NC_ + col] = f2b(acc[mb][nb][reg] + bias);
      }
    }
  }
}

// ------------------------------- scan --------------------------------------
// 64 wgs: group G = g>>5 owns batches [16G,16G+16); wg slice = 32 cols.
// Per step: A) z,r = sig(P + h Uzr^T); write rh  | barrier |
//           B) h~ = tanh(P + rh Uh^T); h update; write Hb/out | barrier |
__device__ __forceinline__ void group_barrier(unsigned* gflags, int gg,
                                              unsigned gen) {
  __syncthreads();  // drains each wave's vmcnt -> all wg stores are in L2
  if (threadIdx.x == 0)
    __hip_atomic_store(gflags + gg, gen, __ATOMIC_RELEASE,
                       __HIP_MEMORY_SCOPE_AGENT);  // agent release: wb L2
  if (threadIdx.x < 32) {
    while (__hip_atomic_load(gflags + threadIdx.x, __ATOMIC_RELAXED,
                             __HIP_MEMORY_SCOPE_AGENT) < gen)
      __builtin_amdgcn_s_sleep(1);
  }
  __threadfence();  // acquire: invalidate L1/L2 so fresh Hb/RH are visible
  __syncthreads();
}

__global__ __launch_bounds__(256, 1) void gru_scan(
    const ushort_t* __restrict__ P, const ushort_t* __restrict__ Uzr,
    const ushort_t* __restrict__ Uh, const float* __restrict__ h0,
    ushort_t* __restrict__ Hb, ushort_t* __restrict__ RH,
    unsigned* __restrict__ flags, float* __restrict__ out) {
  const int g = blockIdx.x;
  const int G = g >> 5, gg = g & 31;
  const int rb0 = G * 16;   // batch base
  const int cs = gg * 32;   // column slice base
  const int tid = threadIdx.x;
  const int w = tid >> 6, l = tid & 63;
  const int quad = l >> 4, lr = l & 15;
  unsigned* gflags = flags + G * 32;

  __shared__ float Hl[16][33];   // fp32 master h slice [row][col-cs]
  __shared__ f32x4 red[2][64];   // phase-B k-split partials

  // phase A: wave w -> (ct = z/r, cb = col sub-block); phase B: (kh, cb)
  const int ctA = w >> 1, cbA = w & 1;
  const int khB = w >> 1, cbB = w & 1;
  const int eA = cs + cbA * 16 + lr;
  const int eB = cs + cbB * 16 + lr;

  // ---- preload weights into VGPRs (persist across all 1024 steps) ----
  bf16x8 wa[32];  // U_z (ct=0) or U_r (ct=1) rows for 16 cols, full K
  {
    const ushort_t* urow = Uzr + (size_t)(ctA * 1024 + eA) * DIM_;
#pragma unroll
    for (int it = 0; it < 32; ++it)
      wa[it] = *(const bf16x8*)(urow + it * 32 + quad * 8);
  }
  bf16x8 wb[16];  // U_h rows for 16 cols, K-half kh
  {
    const ushort_t* urow = Uh + (size_t)eB * DIM_ + khB * 512;
#pragma unroll
    for (int it = 0; it < 16; ++it)
      wb[it] = *(const bf16x8*)(urow + it * 32 + quad * 8);
  }

  // ---- init h slice (fp32 LDS + bf16 global) ----
  for (int s = tid; s < 512; s += 256) {
    int rr = s >> 5, cc = s & 31;
    float v = h0[(rb0 + rr) * DIM_ + cs + cc];
    Hl[rr][cc] = v;
    Hb[(size_t)(rb0 + rr) * DIM_ + cs + cc] = f2b(v);
  }
  unsigned gen = 1;
  group_barrier(gflags, gg, gen);

  const ushort_t* HbA = Hb + (size_t)(rb0 + lr) * DIM_ + quad * 8;
  const ushort_t* RHA = RH + (size_t)(rb0 + lr) * DIM_ + khB * 512 + quad * 8;

  for (int t = 0; t < T_; ++t) {
    const size_t prow = ((size_t)(t * BATCH_ + rb0)) * NC_;
    // prefetch this step's P values (independent of barriers)
    float pA[4], pB[4];
#pragma unroll
    for (int reg = 0; reg < 4; ++reg) {
      int br = quad * 4 + reg;
      pA[reg] = b2f(P[prow + (size_t)br * NC_ + ctA * 1024 + eA]);
      pB[reg] = b2f(P[prow + (size_t)br * NC_ + 2048 + eB]);
    }

    // ---------------- phase A: z and r ----------------
    f32x4 acc = {0.f, 0.f, 0.f, 0.f};
#pragma unroll
    for (int it = 0; it < 32; ++it) {
      bf16x8 a = *(const bf16x8*)(HbA + it * 32);
      acc = __builtin_amdgcn_mfma_f32_16x16x32_bf16(a, wa[it], acc, 0, 0, 0);
    }
    float zv[4];
#pragma unroll
    for (int reg = 0; reg < 4; ++reg) {
      int br = quad * 4 + reg;
      float pre = acc[reg] + pA[reg];
      float sv = 1.f / (1.f + __expf(-pre));
      if (ctA == 0) {
        zv[reg] = sv;  // z stays in registers; same lane mapping in phase B
      } else {
        float hv = Hl[br][cbA * 16 + lr];
        RH[(size_t)(rb0 + br) * DIM_ + eA] = f2b(sv * hv);
      }
    }
    ++gen;
    group_barrier(gflags, gg, gen);

    // ---------------- phase B: h~ and update ----------------
    f32x4 acch = {0.f, 0.f, 0.f, 0.f};
#pragma unroll
    for (int it = 0; it < 16; ++it) {
      bf16x8 a = *(const bf16x8*)(RHA + it * 32);
      acch = __builtin_amdgcn_mfma_f32_16x16x32_bf16(a, wb[it], acch, 0, 0, 0);
    }
    if (w >= 2) red[cbB][l] = acch;
    __syncthreads();
    if (w < 2) {
      f32x4 oth = red[cbB][l];
#pragma unroll
      for (int reg = 0; reg < 4; ++reg) {
        int br = quad * 4 + reg;
        float ax = pB[reg] + acch[reg] + oth[reg];
        // safe tanh: no inf/inf NaN
        float e = __expf(2.f * fabsf(ax));
        float th = copysignf(1.f - 2.f / (e + 1.f), ax);
        float hv = Hl[br][cbB * 16 + lr];
        float z = zv[reg];
        float hn = (1.f - z) * hv + z * th;
        Hl[br][cbB * 16 + lr] = hn;
        int gb = rb0 + br;
        Hb[(size_t)gb * DIM_ + eB] = f2b(hn);
        out[((size_t)t * BATCH_ + gb) * DIM_ + eB] = hn;
      }
    }
    ++gen;
    group_barrier(gflags, gg, gen);
  }
}

// ------------------------------- launch ------------------------------------
extern "C" void kernel_launch(void* const* d_in, const int* in_sizes, int n_in,
                              void* d_out, int out_size, void* d_ws,
                              size_t ws_size, hipStream_t stream) {
  const float* x   = (const float*)d_in[0];
  const float* h0  = (const float*)d_in[1];
  const float* Wzr = (const float*)d_in[2];
  const float* Uzr = (const float*)d_in[3];
  const float* Wh  = (const float*)d_in[4];
  const float* Uh  = (const float*)d_in[5];
  const float* bzr = (const float*)d_in[6];
  const float* bh  = (const float*)d_in[7];
  char* ws = (char*)d_ws;
  ushort_t* P     = (ushort_t*)(ws + OFF_P);
  ushort_t* Xbf   = (ushort_t*)(ws + OFF_XBF);
  ushort_t* Wbf   = (ushort_t*)(ws + OFF_WBF);
  ushort_t* Uzrb  = (ushort_t*)(ws + OFF_UZR);
  ushort_t* Uhb   = (ushort_t*)(ws + OFF_UH);
  ushort_t* Hb    = (ushort_t*)(ws + OFF_HB);
  ushort_t* RH    = (ushort_t*)(ws + OFF_RH);
  unsigned* flags = (unsigned*)(ws + OFF_FLAGS);
  float* out = (float*)d_out;

  zero_flags<<<1, 64, 0, stream>>>(flags);
  cvt_f32_bf16x4<<<1024, 256, 0, stream>>>((const float4*)x, (uint2*)Xbf,
                                           33554432 / 4);
  cvt_f32_bf16x4<<<256, 256, 0, stream>>>((const float4*)Wzr, (uint2*)Wbf,
                                          2097152 / 4);
  cvt_f32_bf16x4<<<128, 256, 0, stream>>>((const float4*)Wh,
                                          (uint2*)(Wbf + 2097152), 1048576 / 4);
  cvt_f32_bf16x4<<<256, 256, 0, stream>>>((const float4*)Uzr, (uint2*)Uzrb,
                                          2097152 / 4);
  cvt_f32_bf16x4<<<128, 256, 0, stream>>>((const float4*)Uh, (uint2*)Uhb,
                                          1048576 / 4);
  gemm_xw<<<6144, 256, 0, stream>>>(Xbf, Wbf, bzr, bh, P);
  gru_scan<<<64, 256, 0, stream>>>(P, Uzrb, Uhb, h0, Hb, RH, flags, out);
}

// Round 2
// 7691.301 us; speedup vs baseline: 2.7865x; 2.7865x over previous
//
#include <hip/hip_runtime.h>

// ---------------------------------------------------------------------------
// GRU scan on MI355X. Phase 1: bf16 GEMM P = X W^T + b. Phase 2: persistent
// scan, 2 groups x 32 wgs, U weights in VGPRs.
// R2 change: ALL cross-wg traffic uses sc0+sc1 (coherence-point) accesses via
// inline asm -> no buffer_wbl2 / buffer_inv cache maintenance in the hot loop.
// Payload staged once per wg into LDS (not once per wave).
// ---------------------------------------------------------------------------

typedef __attribute__((ext_vector_type(8))) __bf16 bf16x8;
typedef __attribute__((ext_vector_type(4))) float f32x4;
typedef unsigned short ushort_t;
typedef unsigned long long u64;

#define DIM_ 1024
#define BATCH_ 32
#define T_ 1024
#define NC_ 3072  // 3*DIM

// workspace layout (bytes)
static constexpr size_t OFF_P     = 0;                    // bf16 32768x3072
static constexpr size_t OFF_XBF   = 201326592;            // bf16 32768x1024
static constexpr size_t OFF_WBF   = OFF_XBF + 67108864;   // bf16 3072x1024
static constexpr size_t OFF_UZR   = OFF_WBF + 6291456;    // bf16 2048x1024
static constexpr size_t OFF_UH    = OFF_UZR + 4194304;    // bf16 1024x1024
static constexpr size_t OFF_HB    = OFF_UH  + 2097152;    // bf16 32x1024
static constexpr size_t OFF_RH    = OFF_HB  + 65536;      // bf16 32x1024
static constexpr size_t OFF_FLAGS = OFF_RH  + 65536;      // 256 B

__device__ __forceinline__ float b2f(ushort_t u) {
  union { float f; unsigned i; } v;
  v.i = ((unsigned)u) << 16;
  return v.f;
}
__device__ __forceinline__ ushort_t f2b(float f) {  // round-to-nearest-even
  union { float f; unsigned i; } v;
  v.f = f;
  unsigned r = v.i + 0x7fffu + ((v.i >> 16) & 1u);
  return (ushort_t)(r >> 16);
}

// --- coherence-point (IF) accessors: bypass L1/L2, no fences needed --------
__device__ __forceinline__ void st_u32_sc(void* p, unsigned v) {
  asm volatile("global_store_dword %0, %1, off sc0 sc1" ::"v"(p), "v"(v)
               : "memory");
}
__device__ __forceinline__ unsigned ld_u32_sc(const void* p) {
  unsigned r;
  asm volatile("global_load_dword %0, %1, off sc0 sc1\n\ts_waitcnt vmcnt(0)"
               : "=v"(r) : "v"(p) : "memory");
  return r;
}
__device__ __forceinline__ u64 ld_u64_sc(const void* p) {  // NO waitcnt!
  u64 r;
  asm volatile("global_load_dwordx2 %0, %1, off sc0 sc1" : "=v"(r) : "v"(p));
  return r;
}
__device__ __forceinline__ void vm_drain() {
  asm volatile("s_waitcnt vmcnt(0)" ::: "memory");
}

// ------------------------------- converts ----------------------------------
__global__ void cvt_f32_bf16x4(const float4* __restrict__ src,
                               uint2* __restrict__ dst, int n4) {
  int i = blockIdx.x * blockDim.x + threadIdx.x;
  int st = gridDim.x * blockDim.x;
  for (; i < n4; i += st) {
    float4 v = src[i];
    unsigned a = (unsigned)f2b(v.x) | ((unsigned)f2b(v.y) << 16);
    unsigned b = (unsigned)f2b(v.z) | ((unsigned)f2b(v.w) << 16);
    dst[i] = make_uint2(a, b);
  }
}

__global__ void zero_flags(unsigned* f) { f[threadIdx.x] = 0u; }

// ------------------------------- GEMM --------------------------------------
__global__ __launch_bounds__(256) void gemm_xw(
    const ushort_t* __restrict__ A, const ushort_t* __restrict__ Bm,
    const float* __restrict__ bzr, const float* __restrict__ bh,
    ushort_t* __restrict__ C) {
  __shared__ ushort_t As[128][40];
  __shared__ ushort_t Bs[128][40];
  const int bi = blockIdx.x;
  const int p = bi / 192;
  const int q = bi % 192;
  const int i0 = (p * 8 + (q & 7)) * 128;
  const int n0 = (q >> 3) * 128;
  const int tid = threadIdx.x;
  const int w = tid >> 6, l = tid & 63;
  const int wr = w >> 1, wc = w & 1;
  const int quad = l >> 4, lr = l & 15;

  f32x4 acc[4][4] = {};
  for (int kc = 0; kc < 1024; kc += 32) {
    __syncthreads();
#pragma unroll
    for (int j = 0; j < 2; ++j) {
      int c = j * 256 + tid;
      int r = c >> 2, pp = c & 3;
      *(int4*)(&As[r][pp * 8]) =
          *(const int4*)(A + (size_t)(i0 + r) * 1024 + kc + pp * 8);
      *(int4*)(&Bs[r][pp * 8]) =
          *(const int4*)(Bm + (size_t)(n0 + r) * 1024 + kc + pp * 8);
    }
    __syncthreads();
    bf16x8 af[4], bfr[4];
#pragma unroll
    for (int mb = 0; mb < 4; ++mb)
      af[mb] = *(const bf16x8*)(&As[wr * 64 + mb * 16 + lr][quad * 8]);
#pragma unroll
    for (int nb = 0; nb < 4; ++nb)
      bfr[nb] = *(const bf16x8*)(&Bs[wc * 64 + nb * 16 + lr][quad * 8]);
#pragma unroll
    for (int mb = 0; mb < 4; ++mb)
#pragma unroll
      for (int nb = 0; nb < 4; ++nb)
        acc[mb][nb] = __builtin_amdgcn_mfma_f32_16x16x32_bf16(
            af[mb], bfr[nb], acc[mb][nb], 0, 0, 0);
  }
#pragma unroll
  for (int nb = 0; nb < 4; ++nb) {
    int col = n0 + wc * 64 + nb * 16 + lr;
    float bias = (col < 2048) ? bzr[col] : bh[col - 2048];
#pragma unroll
    for (int mb = 0; mb < 4; ++mb) {
#pragma unroll
      for (int reg = 0; reg < 4; ++reg) {
        int row = i0 + wr * 64 + mb * 16 + quad * 4 + reg;
        C[(size_t)row * NC_ + col] = f2b(acc[mb][nb][reg] + bias);
      }
    }
  }
}

// ------------------------------- scan --------------------------------------
// barrier: per-wave vmcnt drain -> syncthreads -> flag store (sc0sc1) ->
// 32-lane poll (sc0sc1) -> syncthreads. No cache maintenance anywhere.
__device__ __forceinline__ void group_barrier(unsigned* gflags, int gg,
                                              unsigned gen, int tid) {
  vm_drain();       // this wave's sc1 payload stores are at the IF
  __syncthreads();  // all waves of wg drained
  if (tid == 0) st_u32_sc(gflags + gg, gen);
  if (tid < 32) {
    while (ld_u32_sc(gflags + tid) < gen) __builtin_amdgcn_s_sleep(1);
  }
  __syncthreads();
}

__global__ __launch_bounds__(256, 1) void gru_scan(
    const ushort_t* __restrict__ P, const ushort_t* __restrict__ Uzr,
    const ushort_t* __restrict__ Uh, const float* __restrict__ h0,
    ushort_t* __restrict__ Hb, ushort_t* __restrict__ RH,
    unsigned* __restrict__ flags, float* __restrict__ out) {
  const int g = blockIdx.x;
  const int G = g >> 5, gg = g & 31;
  const int rb0 = G * 16;   // batch base
  const int cs = gg * 32;   // column slice base
  const int tid = threadIdx.x;
  const int w = tid >> 6, l = tid & 63;
  const int quad = l >> 4, lr = l & 15;
  unsigned* gflags = flags + G * 32;

  // staged payload (full 16x1024 of Hb in phase A / RH in phase B)
  __shared__ ushort_t StageL[16][1032];  // stride 2064B: 16B-aligned, 2-way bk
  __shared__ float Hl[16][33];           // fp32 master h slice
  __shared__ f32x4 red[2][64];           // phase-B k-split partials

  const int ctA = w >> 1, cbA = w & 1;
  const int khB = w >> 1, cbB = w & 1;
  const int eA = cs + cbA * 16 + lr;
  const int eB = cs + cbB * 16 + lr;

  // ---- preload weights into VGPRs ----
  bf16x8 wa[32];
  {
    const ushort_t* urow = Uzr + (size_t)(ctA * 1024 + eA) * DIM_;
#pragma unroll
    for (int it = 0; it < 32; ++it)
      wa[it] = *(const bf16x8*)(urow + it * 32 + quad * 8);
  }
  bf16x8 wb[16];
  {
    const ushort_t* urow = Uh + (size_t)eB * DIM_ + khB * 512;
#pragma unroll
    for (int it = 0; it < 16; ++it)
      wb[it] = *(const bf16x8*)(urow + it * 32 + quad * 8);
  }

  // ---- init h slice: fp32 LDS master + packed sc1 global ----
  {
    int rr = tid >> 4, cp = tid & 15;
    int c0 = cp * 2;
    float v0 = h0[(rb0 + rr) * DIM_ + cs + c0];
    float v1 = h0[(rb0 + rr) * DIM_ + cs + c0 + 1];
    Hl[rr][c0] = v0;
    Hl[rr][c0 + 1] = v1;
    unsigned pk = (unsigned)f2b(v0) | ((unsigned)f2b(v1) << 16);
    st_u32_sc(&Hb[(size_t)(rb0 + rr) * DIM_ + cs + c0], pk);
  }

  // prefetch P for t=0 (plain cached loads; overlap with init barrier)
  float pA[4], pB[4];
  {
    const size_t prow = (size_t)rb0 * NC_;
#pragma unroll
    for (int reg = 0; reg < 4; ++reg) {
      int br = quad * 4 + reg;
      pA[reg] = b2f(P[prow + (size_t)br * NC_ + ctA * 1024 + eA]);
      pB[reg] = b2f(P[prow + (size_t)br * NC_ + 2048 + eB]);
    }
  }

  unsigned gen = 1;
  group_barrier(gflags, gg, gen, tid);

  for (int t = 0; t < T_; ++t) {
    // ---------------- stage Hb (16x1024 bf16) into LDS ----------------
    {
      u64 tmp[16];
#pragma unroll
      for (int j = 0; j < 16; ++j)
        tmp[j] =
            ld_u64_sc((const u64*)(Hb + (size_t)(rb0 + j) * DIM_) + tid);
      vm_drain();
#pragma unroll
      for (int j = 0; j < 16; ++j) *(u64*)&StageL[j][tid * 4] = tmp[j];
    }
    __syncthreads();

    // ---------------- phase A: z and r ----------------
    f32x4 acc = {0.f, 0.f, 0.f, 0.f};
#pragma unroll
    for (int it = 0; it < 32; ++it) {
      bf16x8 a = *(const bf16x8*)&StageL[lr][it * 32 + quad * 8];
      acc = __builtin_amdgcn_mfma_f32_16x16x32_bf16(a, wa[it], acc, 0, 0, 0);
    }
    float zv[4];
#pragma unroll
    for (int reg = 0; reg < 4; ++reg) {
      int br = quad * 4 + reg;
      float pre = acc[reg] + pA[reg];
      float sv = 1.f / (1.f + __expf(-pre));
      if (ctA == 0) {
        zv[reg] = sv;  // z stays in registers (same lane map in phase B)
      } else {
        float hv = Hl[br][cbA * 16 + lr];
        unsigned own = f2b(sv * hv);
        unsigned oth = (unsigned)__shfl_xor((int)own, 1);
        if ((l & 1) == 0) {
          unsigned pk = own | (oth << 16);
          st_u32_sc(&RH[(size_t)(rb0 + br) * DIM_ + eA], pk);
        }
      }
    }
    ++gen;
    group_barrier(gflags, gg, gen, tid);

    // ---------------- stage RH (16x1024 bf16) into LDS ----------------
    {
      u64 tmp[16];
#pragma unroll
      for (int j = 0; j < 16; ++j)
        tmp[j] =
            ld_u64_sc((const u64*)(RH + (size_t)(rb0 + j) * DIM_) + tid);
      vm_drain();
#pragma unroll
      for (int j = 0; j < 16; ++j) *(u64*)&StageL[j][tid * 4] = tmp[j];
    }
    __syncthreads();

    // ---------------- phase B: h~ and update ----------------
    f32x4 acch = {0.f, 0.f, 0.f, 0.f};
#pragma unroll
    for (int it = 0; it < 16; ++it) {
      bf16x8 a = *(const bf16x8*)&StageL[lr][khB * 512 + it * 32 + quad * 8];
      acch = __builtin_amdgcn_mfma_f32_16x16x32_bf16(a, wb[it], acch, 0, 0, 0);
    }
    if (w >= 2) red[cbB][l] = acch;
    __syncthreads();
    if (w < 2) {
      f32x4 oth4 = red[cbB][l];
#pragma unroll
      for (int reg = 0; reg < 4; ++reg) {
        int br = quad * 4 + reg;
        float ax = pB[reg] + acch[reg] + oth4[reg];
        float e = __expf(2.f * fabsf(ax));
        float th = copysignf(1.f - 2.f / (e + 1.f), ax);
        float hv = Hl[br][cbB * 16 + lr];
        float z = zv[reg];
        float hn = (1.f - z) * hv + z * th;
        Hl[br][cbB * 16 + lr] = hn;
        int gb = rb0 + br;
        // packed sc1 h store for other wgs
        unsigned own = f2b(hn);
        unsigned otherh = (unsigned)__shfl_xor((int)own, 1);
        float hn_oth = __shfl_xor(hn, 1);
        if ((l & 1) == 0) {
          st_u32_sc(&Hb[(size_t)gb * DIM_ + eB], own | (otherh << 16));
          *(float2*)&out[((size_t)t * BATCH_ + gb) * DIM_ + eB] =
              make_float2(hn, hn_oth);
        }
      }
    }

    // prefetch P for t+1 (completes during the barrier's vmcnt drain)
    {
      int tn = (t + 1 < T_) ? t + 1 : t;
      const size_t prow = ((size_t)(tn * BATCH_ + rb0)) * NC_;
#pragma unroll
      for (int reg = 0; reg < 4; ++reg) {
        int br = quad * 4 + reg;
        pA[reg] = b2f(P[prow + (size_t)br * NC_ + ctA * 1024 + eA]);
        pB[reg] = b2f(P[prow + (size_t)br * NC_ + 2048 + eB]);
      }
    }
    ++gen;
    group_barrier(gflags, gg, gen, tid);
  }
}

// ------------------------------- launch ------------------------------------
extern "C" void kernel_launch(void* const* d_in, const int* in_sizes, int n_in,
                              void* d_out, int out_size, void* d_ws,
                              size_t ws_size, hipStream_t stream) {
  const float* x   = (const float*)d_in[0];
  const float* h0  = (const float*)d_in[1];
  const float* Wzr = (const float*)d_in[2];
  const float* Uzr = (const float*)d_in[3];
  const float* Wh  = (const float*)d_in[4];
  const float* Uh  = (const float*)d_in[5];
  const float* bzr = (const float*)d_in[6];
  const float* bh  = (const float*)d_in[7];
  char* ws = (char*)d_ws;
  ushort_t* P     = (ushort_t*)(ws + OFF_P);
  ushort_t* Xbf   = (ushort_t*)(ws + OFF_XBF);
  ushort_t* Wbf   = (ushort_t*)(ws + OFF_WBF);
  ushort_t* Uzrb  = (ushort_t*)(ws + OFF_UZR);
  ushort_t* Uhb   = (ushort_t*)(ws + OFF_UH);
  ushort_t* Hb    = (ushort_t*)(ws + OFF_HB);
  ushort_t* RH    = (ushort_t*)(ws + OFF_RH);
  unsigned* flags = (unsigned*)(ws + OFF_FLAGS);
  float* out = (float*)d_out;

  zero_flags<<<1, 64, 0, stream>>>(flags);
  cvt_f32_bf16x4<<<1024, 256, 0, stream>>>((const float4*)x, (uint2*)Xbf,
                                           33554432 / 4);
  cvt_f32_bf16x4<<<256, 256, 0, stream>>>((const float4*)Wzr, (uint2*)Wbf,
                                          2097152 / 4);
  cvt_f32_bf16x4<<<128, 256, 0, stream>>>((const float4*)Wh,
                                          (uint2*)(Wbf + 2097152), 1048576 / 4);
  cvt_f32_bf16x4<<<256, 256, 0, stream>>>((const float4*)Uzr, (uint2*)Uzrb,
                                          2097152 / 4);
  cvt_f32_bf16x4<<<128, 256, 0, stream>>>((const float4*)Uh, (uint2*)Uhb,
                                          1048576 / 4);
  gemm_xw<<<6144, 256, 0, stream>>>(Xbf, Wbf, bzr, bh, P);
  gru_scan<<<64, 256, 0, stream>>>(P, Uzrb, Uhb, h0, Hb, RH, flags, out);
}